// Round 10
// baseline (14612.474 us; speedup 1.0000x reference)
//
#include <hip/hip_runtime.h>
#include <stdint.h>
#include <stddef.h>

typedef unsigned short u16;
typedef unsigned int u32;
typedef unsigned long long u64;
typedef __attribute__((ext_vector_type(8))) short short8;
typedef __attribute__((ext_vector_type(4))) float f32x4;
typedef __attribute__((ext_vector_type(2))) float f32x2;

#define B_    512
#define T_    1024
#define TM1_  1023
#define I_    32
#define E_    32
#define H_    256
#define GSZ   4           // blocks per group (dim slices)
#define NGRP  32          // number of groups
#define NTH   512         // threads per block (8 waves)
#define MBOX_PAR (B_ * H_)                 // u32 words per mailbox parity (131072)
#define OUTY_STRIDE (TM1_ * I_)            // 32736
#define OUTH_BASE ((size_t)B_ * TM1_ * I_) // 16760832

__device__ __forceinline__ u16 f2bf(float f) {
  union { float f; unsigned int i; } c;
  c.f = f;
  unsigned int x = c.i;
  x += 0x7FFFu + ((x >> 16) & 1u);   // round-to-nearest-even
  return (u16)(x >> 16);
}
__device__ __forceinline__ short8 ld8bf(const float* p) {
  short8 rv;
#pragma unroll
  for (int j = 0; j < 8; ++j) rv[j] = (short)f2bf(p[j]);
  return rv;
}
// vectorized variant for the per-step weight streaming (32-B aligned rows)
__device__ __forceinline__ short8 ld8bfv(const float* p) {
  f32x4 v0 = *(const f32x4*)(p);
  f32x4 v1 = *(const f32x4*)(p + 4);
  short8 rv;
#pragma unroll
  for (int j = 0; j < 4; ++j) { rv[j] = (short)f2bf(v0[j]); rv[4 + j] = (short)f2bf(v1[j]); }
  return rv;
}
__device__ __forceinline__ float sigm(float x) { return 1.f / (1.f + __expf(-x)); }
__device__ __forceinline__ float tanh_fast(float x) {
  x = fminf(15.f, fmaxf(-15.f, x));
  float e = __expf(2.f * x);
  return (e - 1.f) / (e + 1.f);
}
// volatile => sc0 sc1 on gfx950: device/system scope, compiler no-reorder.
// PROVEN cross-XCD-correct (r0/r2/r4/r7). sc0-only is CU scope (r5) — never weaken.
__device__ __forceinline__ u64 ldq_cp(const u64* p) { return *(volatile const u64*)p; }
__device__ __forceinline__ void stw_cp(u32* p, u32 v) { *(volatile u32*)p = v; }

// Persistent 2-layer GRU. Grid = 128 blocks, 512 thr (8 waves).
// 32 groups x 4 blocks. Group g owns batch rows [g*16,g*16+16); block r owns
// h-dims [r*64,r*64+64) of both layers.
//
// r10 rationale: bytes model (r4/r6/r7) says dur/step ~= coherent bytes/step
// / ~1.06 TB/s; GSZ 8->4 halves mailbox read redundancy. r8/r9 (same GSZ=4)
// died to a source-correlated container kill — suspected RA pathology from a
// 48-frag register mega-array (44-48 live frags on two roles). This version
// caps resident frags at 32/wave (r4 proved 34 compiles fine) by STREAMING
// the fat L1 r/z weights (K=512) from global fp32 each step (L2-resident,
// plain cached loads — not the coherent path) with per-use bf16 convert.
// Wave map (8 waves = 4 gates x 2 N32-halves, P = w&1):
//   gt0: A = L0-r resident wfA[20];  B = L1-r STREAMED (whh1 ph7, wih1 ph9)
//   gt1: A = L0-z resident wfA[20];  B = L1-z STREAMED
//   gt2: A = L0-i_n wfA[0..3];      B = L1-i_n wfB[16] (ph9); + readout wfY[8]
//   gt3: A = L0-h_n wfA[0..15];     B = L1-h_n wfB[16] (ph7)
//
// Sync: TAGGED MAILBOXES (r4, proven): word = bf16(h)<<16 | (step+1).
// Consumer polls its own 8 words (4 u64 loads) — the detecting load IS the
// data (1 RT/hop). Parity double-buffer bounds producer lead (r4 argument).
// Hang-proof bounded spins; s_sleep(4) re-poll backoff; publishes are two
// proven stw_cp u32 stores per thread.
__global__ __launch_bounds__(NTH, 1)
void arrnn_persistent(
    const float* __restrict__ X, const float* __restrict__ ENC, const int* __restrict__ MASK,
    const float* __restrict__ wih0, const float* __restrict__ whh0,
    const float* __restrict__ bih0, const float* __restrict__ bhh0,
    const float* __restrict__ wih1, const float* __restrict__ whh1,
    const float* __restrict__ bih1, const float* __restrict__ bhh1,
    const float* __restrict__ wout, const float* __restrict__ bout,
    float* __restrict__ out, u32* __restrict__ h0m, u32* __restrict__ h1m)
{
  __shared__ __align__(16) u16 sH0buf[16 * 264];   // 8448 B  h0 staged
  __shared__ __align__(16) u16 sH1buf[16 * 264];   // 8448 B  h1 staged
  __shared__ __align__(16) u16 sXE[16 * 72];       // 2304 B  [x|e]
  __shared__ float sG[4 * 16 * 68];                // 17408 B gates [gate][row][64+pad]
  __shared__ float sH0loc[1024];                   // 4096 B  fp32 carry (16x64)
  __shared__ float sH1loc[1024];
  __shared__ float sY[16 * 36];                    // 2304 B
  __shared__ int   sMk[16];

  const int tid  = threadIdx.x;
  const int w    = tid >> 6;          // wave 0..7
  const int lane = tid & 63;
  const int quad = lane >> 4;         // 0..3
  const int l15  = lane & 15;
  const int g    = blockIdx.x >> 2;   // group 0..31
  const int r    = blockIdx.x & 3;    // slice 0..3
  const int hs   = r << 6;            // h-dim base of this block's 64-dim slice
  const int row0 = g << 4;            // batch row base of group (16 rows)
  const int gt   = w >> 1;            // 0=r, 1=z, 2=i_n, 3=h_n
  const int P    = w & 1;             // N32-half: dims [P*32, P*32+32)
  const int toff = P << 5;
  const int crow = tid >> 5;          // staging/combine: row 0..15
  const int p32  = tid & 31;          // staging: u64-quad idx / combine: dim-pair

  short8 zero8 = {0, 0, 0, 0, 0, 0, 0, 0};

  // ---- preload resident weight B-fragments (fp32 -> bf16, once) ----
  const int n0 = hs + toff + l15;     // tile j=0 gate-dim (within 256)
  const int n1 = n0 + 16;             // tile j=1 gate-dim

  short8 wfA[20];
#pragma unroll
  for (int i = 0; i < 20; ++i) wfA[i] = zero8;
  short8 wfB[16];
#pragma unroll
  for (int i = 0; i < 16; ++i) wfB[i] = zero8;
  short8 wfY[8];
#pragma unroll
  for (int i = 0; i < 8; ++i) wfY[i] = zero8;

  float boutv = 0.f;
  if (gt <= 1) {
    const int gb = (gt == 1) ? 256 : 0;
#pragma unroll
    for (int j = 0; j < 2; ++j) {
      const int n = j ? n1 : n0;
#pragma unroll
      for (int kk = 0; kk < 10; ++kk) {          // A: L0 r/z, K=320
        const int k = kk * 32 + quad * 8;
        const float* p = (kk < 2) ? (wih0 + (gb + n) * 64 + k)
                                  : (whh0 + (gb + n) * 256 + (k - 64));
        wfA[j * 10 + kk] = ld8bf(p);
      }
    }
  } else if (gt == 2) {
#pragma unroll
    for (int j = 0; j < 2; ++j) {
      const int n = j ? n1 : n0;
#pragma unroll
      for (int kk = 0; kk < 2; ++kk)             // A: L0 i_n (xe only)
        wfA[j * 2 + kk] = ld8bf(wih0 + (512 + n) * 64 + kk * 32 + quad * 8);
#pragma unroll
      for (int kk = 0; kk < 8; ++kk)             // B: L1 i_n over h0
        wfB[j * 8 + kk] = ld8bf(wih1 + (512 + n) * 256 + kk * 32 + quad * 8);
    }
    const int ycol = (P << 4) + l15;             // readout cols
#pragma unroll
    for (int kk = 0; kk < 8; ++kk)
      wfY[kk] = ld8bf(wout + ycol * 256 + kk * 32 + quad * 8);
    boutv = bout[ycol];
  } else {                                        // gt == 3
#pragma unroll
    for (int j = 0; j < 2; ++j) {
      const int n = j ? n1 : n0;
#pragma unroll
      for (int kk = 0; kk < 8; ++kk)             // A: L0 h_n over h0
        wfA[j * 8 + kk] = ld8bf(whh0 + (512 + n) * 256 + kk * 32 + quad * 8);
#pragma unroll
      for (int kk = 0; kk < 8; ++kk)             // B: L1 h_n over h1
        wfB[j * 8 + kk] = ld8bf(whh1 + (512 + n) * 256 + kk * 32 + quad * 8);
    }
  }

  // streamed-weight row bases for gt<=1 (L1 r/z)
  const int gb1 = (gt == 1) ? 256 : 0;
  const float* wS7a = whh1 + (gb1 + n0) * 256 + quad * 8;   // phase 7 tile 0
  const float* wS7b = whh1 + (gb1 + n1) * 256 + quad * 8;   // phase 7 tile 1
  const float* wS9a = wih1 + (gb1 + n0) * 256 + quad * 8;   // phase 9 tile 0
  const float* wS9b = wih1 + (gb1 + n1) * 256 + quad * 8;   // phase 9 tile 1

  // biases: combine thread handles dims bd0 = hs+2*p32, bd1 = bd0+1
  const int bd0 = hs + 2 * p32, bd1 = bd0 + 1;
  const float b0r0 = bih0[bd0] + bhh0[bd0],             b0r1 = bih0[bd1] + bhh0[bd1];
  const float b0z0 = bih0[256 + bd0] + bhh0[256 + bd0], b0z1 = bih0[256 + bd1] + bhh0[256 + bd1];
  const float b0i0 = bih0[512 + bd0],                   b0i1 = bih0[512 + bd1];
  const float b0h0 = bhh0[512 + bd0],                   b0h1 = bhh0[512 + bd1];
  const float b1r0 = bih1[bd0] + bhh1[bd0],             b1r1 = bih1[bd1] + bhh1[bd1];
  const float b1z0 = bih1[256 + bd0] + bhh1[256 + bd0], b1z1 = bih1[256 + bd1] + bhh1[256 + bd1];
  const float b1i0 = bih1[512 + bd0],                   b1i1 = bih1[512 + bd1];
  const float b1h0 = bhh1[512 + bd0],                   b1h1 = bhh1[512 + bd1];

  // zero LDS h bufs (t=0 reads them) + fp32 carries
  for (int i = tid; i < 2112; i += NTH) {
    ((u32*)sH0buf)[i] = 0u;
    ((u32*)sH1buf)[i] = 0u;
  }
  for (int i = tid; i < 1024; i += NTH) { sH0loc[i] = 0.f; sH1loc[i] = 0.f; }
  __syncthreads();

  int alive = 1;
  const int b = row0 + crow;          // this thread's staging/combine batch row

  // Poll own 8 words (tag == exp in every word), then unpack bf16 payload.
#define SPIN_STAGE(mboxu32, expTag, dstbuf)                                      \
  do {                                                                           \
    const u64* qp = (const u64*)(mboxu32) + (size_t)b * 128 + p32 * 4;           \
    const u64 tagp = (u64)(u32)(expTag) | ((u64)(u32)(expTag) << 32);            \
    u64 q0, q1, q2, q3;                                                          \
    int it = 0;                                                                  \
    for (;;) {                                                                   \
      q0 = ldq_cp(qp); q1 = ldq_cp(qp + 1); q2 = ldq_cp(qp + 2); q3 = ldq_cp(qp + 3); \
      u64 dd = ((q0 ^ tagp) | (q1 ^ tagp) | (q2 ^ tagp) | (q3 ^ tagp))           \
               & 0x0000FFFF0000FFFFull;                                          \
      if (dd == 0 || !alive) break;                                              \
      __builtin_amdgcn_s_sleep(4);                                               \
      if (++it > (1 << 15)) { alive = 0; break; }                                \
    }                                                                            \
    short8 sv;                                                                   \
    sv[0] = (short)(u16)(q0 >> 16); sv[1] = (short)(u16)(q0 >> 48);              \
    sv[2] = (short)(u16)(q1 >> 16); sv[3] = (short)(u16)(q1 >> 48);              \
    sv[4] = (short)(u16)(q2 >> 16); sv[5] = (short)(u16)(q2 >> 48);              \
    sv[6] = (short)(u16)(q3 >> 16); sv[7] = (short)(u16)(q3 >> 48);              \
    *(short8*)((dstbuf) + crow * 264 + p32 * 8) = sv;                            \
  } while (0)

  for (int t = 0; t < 1024; ++t) {
    const int par = t & 1;

    // ---- (a) stage x/e/mask into sXE (masked-x cols filled later from y) ----
    if (t < 1023) {
      if (p32 < 16) {
        int mk = 1;
        if (t > 0) mk = (MASK[b * T_ + t] != 0);
        f32x2 xld = *(const f32x2*)(X + ((size_t)b * T_ + t) * I_ + 2 * p32);
        if (mk) { sXE[crow * 72 + 2 * p32] = f2bf(xld.x);
                  sXE[crow * 72 + 2 * p32 + 1] = f2bf(xld.y); }
        if (p32 == 0) sMk[crow] = mk;
      } else {
        const int c2 = p32 - 16;
        f32x2 eld = *(const f32x2*)(ENC + ((size_t)b * T_ + t + 1) * E_ + 2 * c2);
        sXE[crow * 72 + 32 + 2 * c2] = f2bf(eld.x);
        sXE[crow * 72 + 32 + 2 * c2 + 1] = f2bf(eld.y);
      }
    }

    // ---- (1) phase A, h0(t-1)-part GEMM (sH0buf stable since prev step) ----
    f32x4 a0 = {0.f, 0.f, 0.f, 0.f}, a1 = {0.f, 0.f, 0.f, 0.f};
    if (t < 1023) {
      const u16* ah = sH0buf + l15 * 264 + quad * 8;
      if (gt <= 1) {
#pragma unroll
        for (int kk = 2; kk < 10; ++kk) {
          short8 af = *(const short8*)(ah + (kk - 2) * 32);
          a0 = __builtin_amdgcn_mfma_f32_16x16x32_bf16(af, wfA[kk], a0, 0, 0, 0);
          a1 = __builtin_amdgcn_mfma_f32_16x16x32_bf16(af, wfA[10 + kk], a1, 0, 0, 0);
        }
      } else if (gt == 3) {
#pragma unroll
        for (int kk = 0; kk < 8; ++kk) {
          short8 af = *(const short8*)(ah + kk * 32);
          a0 = __builtin_amdgcn_mfma_f32_16x16x32_bf16(af, wfA[kk], a0, 0, 0, 0);
          a1 = __builtin_amdgcn_mfma_f32_16x16x32_bf16(af, wfA[8 + kk], a1, 0, 0, 0);
        }
      }
    }

    // ---- (2) poll h1(t-1) mailbox (tag t), stage sH1buf ----
    if (t > 0) SPIN_STAGE(h1m + (size_t)par * MBOX_PAR, t, sH1buf);
    __syncthreads();   // B1

    // ---- (3) readout y(t-1): gt==2 waves ----
    if (t > 0 && gt == 2) {
      const u16* ap = sH1buf + l15 * 264 + quad * 8;
      f32x4 ay = {0.f, 0.f, 0.f, 0.f};
#pragma unroll
      for (int kk = 0; kk < 8; ++kk)
        ay = __builtin_amdgcn_mfma_f32_16x16x32_bf16(
            *(const short8*)(ap + kk * 32), wfY[kk], ay, 0, 0, 0);
#pragma unroll
      for (int rg = 0; rg < 4; ++rg)
        sY[(quad * 4 + rg) * 36 + (P << 4) + l15] = ay[rg] + boutv;
    }
    __syncthreads();   // B2

    // ---- (4) write out y(t-1); feed masked-x columns of sXE from y ----
    if (t > 0) {
      if (tid < 128) {
        const int lr = (r << 2) + (tid >> 5);   // this block's 4 rows
        const int lc = tid & 31;
        out[(size_t)(row0 + lr) * OUTY_STRIDE + (size_t)(t - 1) * I_ + lc] =
            sY[lr * 36 + lc];
      }
      if (t < 1023 && p32 < 16 && !sMk[crow]) {
        sXE[crow * 72 + 2 * p32]     = f2bf(sY[crow * 36 + 2 * p32]);
        sXE[crow * 72 + 2 * p32 + 1] = f2bf(sY[crow * 36 + 2 * p32 + 1]);
      }
    }
    if (t == 1023) break;
    __syncthreads();   // B3

    // ---- (5) phase A, xe-part GEMM + publish gates (gate idx = gt) ----
    {
      const u16* ax = sXE + l15 * 72 + quad * 8;
      if (gt <= 1) {
#pragma unroll
        for (int kk = 0; kk < 2; ++kk) {
          short8 af = *(const short8*)(ax + kk * 32);
          a0 = __builtin_amdgcn_mfma_f32_16x16x32_bf16(af, wfA[kk], a0, 0, 0, 0);
          a1 = __builtin_amdgcn_mfma_f32_16x16x32_bf16(af, wfA[10 + kk], a1, 0, 0, 0);
        }
      } else if (gt == 2) {
#pragma unroll
        for (int kk = 0; kk < 2; ++kk) {
          short8 af = *(const short8*)(ax + kk * 32);
          a0 = __builtin_amdgcn_mfma_f32_16x16x32_bf16(af, wfA[kk], a0, 0, 0, 0);
          a1 = __builtin_amdgcn_mfma_f32_16x16x32_bf16(af, wfA[2 + kk], a1, 0, 0, 0);
        }
      }
#pragma unroll
      for (int rg = 0; rg < 4; ++rg) {
        const int row = quad * 4 + rg;
        sG[(gt * 16 + row) * 68 + toff + l15]      = a0[rg];
        sG[(gt * 16 + row) * 68 + toff + 16 + l15] = a1[rg];
      }
    }
    __syncthreads();   // B4

    // ---- (6) combine -> h0(t); two tagged stw_cp per thread ----
    {
      const int d0 = 2 * p32, d1 = d0 + 1;
      const float gr0 = sG[(0 * 16 + crow) * 68 + d0] + b0r0;
      const float gz0 = sG[(1 * 16 + crow) * 68 + d0] + b0z0;
      const float gi0 = sG[(2 * 16 + crow) * 68 + d0] + b0i0;
      const float gh0 = sG[(3 * 16 + crow) * 68 + d0] + b0h0;
      const float gr1 = sG[(0 * 16 + crow) * 68 + d1] + b0r1;
      const float gz1 = sG[(1 * 16 + crow) * 68 + d1] + b0z1;
      const float gi1 = sG[(2 * 16 + crow) * 68 + d1] + b0i1;
      const float gh1 = sG[(3 * 16 + crow) * 68 + d1] + b0h1;
      const float rr0 = sigm(gr0), rr1 = sigm(gr1);
      const float zz0 = sigm(gz0), zz1 = sigm(gz1);
      const float nn0 = tanh_fast(gi0 + rr0 * gh0);
      const float nn1 = tanh_fast(gi1 + rr1 * gh1);
      const float hv0 = (1.f - zz0) * nn0 + zz0 * sH0loc[crow * 64 + d0];
      const float hv1 = (1.f - zz1) * nn1 + zz1 * sH0loc[crow * 64 + d1];
      sH0loc[crow * 64 + d0] = hv0;
      sH0loc[crow * 64 + d1] = hv1;
      u32* dst = h0m + (size_t)(par ^ 1) * MBOX_PAR + (size_t)b * H_ + hs + d0;
      stw_cp(dst,     ((u32)f2bf(hv0) << 16) | (u32)(t + 1));
      stw_cp(dst + 1, ((u32)f2bf(hv1) << 16) | (u32)(t + 1));
    }

    // ---- (7) phase B, h1(t-1)-part GEMM (overlaps the h0 hop) ----
    f32x4 c0 = {0.f, 0.f, 0.f, 0.f}, c1 = {0.f, 0.f, 0.f, 0.f};
    {
      const u16* a1p = sH1buf + l15 * 264 + quad * 8;
      if (gt <= 1) {           // L1 r/z, whh1 half: STREAMED
#pragma unroll
        for (int kk = 0; kk < 8; ++kk) {
          short8 af = *(const short8*)(a1p + kk * 32);
          c0 = __builtin_amdgcn_mfma_f32_16x16x32_bf16(af, ld8bfv(wS7a + kk * 32), c0, 0, 0, 0);
          c1 = __builtin_amdgcn_mfma_f32_16x16x32_bf16(af, ld8bfv(wS7b + kk * 32), c1, 0, 0, 0);
        }
      } else if (gt == 3) {    // L1 h_n over h1: resident
#pragma unroll
        for (int kk = 0; kk < 8; ++kk) {
          short8 af = *(const short8*)(a1p + kk * 32);
          c0 = __builtin_amdgcn_mfma_f32_16x16x32_bf16(af, wfB[kk], c0, 0, 0, 0);
          c1 = __builtin_amdgcn_mfma_f32_16x16x32_bf16(af, wfB[8 + kk], c1, 0, 0, 0);
        }
      }
    }

    // ---- (8) poll h0(t) mailbox (tag t+1), stage sH0buf ----
    SPIN_STAGE(h0m + (size_t)(par ^ 1) * MBOX_PAR, t + 1, sH0buf);
    __syncthreads();   // B5 (also separates (6) sG reads from (9) writes)

    // ---- (9) phase B, h0(t)-part GEMM + publish gates (gate idx = gt) ----
    {
      const u16* a0p = sH0buf + l15 * 264 + quad * 8;
      if (gt <= 1) {           // L1 r/z, wih1 half: STREAMED
#pragma unroll
        for (int kk = 0; kk < 8; ++kk) {
          short8 af = *(const short8*)(a0p + kk * 32);
          c0 = __builtin_amdgcn_mfma_f32_16x16x32_bf16(af, ld8bfv(wS9a + kk * 32), c0, 0, 0, 0);
          c1 = __builtin_amdgcn_mfma_f32_16x16x32_bf16(af, ld8bfv(wS9b + kk * 32), c1, 0, 0, 0);
        }
      } else if (gt == 2) {    // L1 i_n over h0: resident
#pragma unroll
        for (int kk = 0; kk < 8; ++kk) {
          short8 af = *(const short8*)(a0p + kk * 32);
          c0 = __builtin_amdgcn_mfma_f32_16x16x32_bf16(af, wfB[kk], c0, 0, 0, 0);
          c1 = __builtin_amdgcn_mfma_f32_16x16x32_bf16(af, wfB[8 + kk], c1, 0, 0, 0);
        }
      }
#pragma unroll
      for (int rg = 0; rg < 4; ++rg) {
        const int row = quad * 4 + rg;
        sG[(gt * 16 + row) * 68 + toff + l15]      = c0[rg];
        sG[(gt * 16 + row) * 68 + toff + 16 + l15] = c1[rg];
      }
    }
    __syncthreads();   // B6

    // ---- (10) combine -> h1(t); two tagged stw_cp per thread ----
    {
      const int d0 = 2 * p32, d1 = d0 + 1;
      const float gr0 = sG[(0 * 16 + crow) * 68 + d0] + b1r0;
      const float gz0 = sG[(1 * 16 + crow) * 68 + d0] + b1z0;
      const float gi0 = sG[(2 * 16 + crow) * 68 + d0] + b1i0;
      const float gh0 = sG[(3 * 16 + crow) * 68 + d0] + b1h0;
      const float gr1 = sG[(0 * 16 + crow) * 68 + d1] + b1r1;
      const float gz1 = sG[(1 * 16 + crow) * 68 + d1] + b1z1;
      const float gi1 = sG[(2 * 16 + crow) * 68 + d1] + b1i1;
      const float gh1 = sG[(3 * 16 + crow) * 68 + d1] + b1h1;
      const float rr0 = sigm(gr0), rr1 = sigm(gr1);
      const float zz0 = sigm(gz0), zz1 = sigm(gz1);
      const float nn0 = tanh_fast(gi0 + rr0 * gh0);
      const float nn1 = tanh_fast(gi1 + rr1 * gh1);
      const float hv0 = (1.f - zz0) * nn0 + zz0 * sH1loc[crow * 64 + d0];
      const float hv1 = (1.f - zz1) * nn1 + zz1 * sH1loc[crow * 64 + d1];
      sH1loc[crow * 64 + d0] = hv0;
      sH1loc[crow * 64 + d1] = hv1;
      u32* dst = h1m + (size_t)(par ^ 1) * MBOX_PAR + (size_t)b * H_ + hs + d0;
      stw_cp(dst,     ((u32)f2bf(hv0) << 16) | (u32)(t + 1));
      stw_cp(dst + 1, ((u32)f2bf(hv1) << 16) | (u32)(t + 1));
    }
  }

  // final hidden state h1(T-2): own fp32 slice (2 dims/thread)
  out[OUTH_BASE + (size_t)b * H_ + hs + 2 * p32]     = sH1loc[crow * 64 + 2 * p32];
  out[OUTH_BASE + (size_t)b * H_ + hs + 2 * p32 + 1] = sH1loc[crow * 64 + 2 * p32 + 1];
#undef SPIN_STAGE
}

extern "C" void kernel_launch(void* const* d_in, const int* in_sizes, int n_in,
                              void* d_out, int out_size, void* d_ws, size_t ws_size,
                              hipStream_t stream) {
  (void)in_sizes; (void)n_in; (void)out_size; (void)ws_size;
  const float* X    = (const float*)d_in[0];
  const float* ENC  = (const float*)d_in[1];
  const int*   MASK = (const int*)d_in[2];
  const float* wih0 = (const float*)d_in[3];
  const float* whh0 = (const float*)d_in[4];
  const float* bih0 = (const float*)d_in[5];
  const float* bhh0 = (const float*)d_in[6];
  const float* wih1 = (const float*)d_in[7];
  const float* whh1 = (const float*)d_in[8];
  const float* bih1 = (const float*)d_in[9];
  const float* bhh1 = (const float*)d_in[10];
  const float* wout = (const float*)d_in[11];
  const float* bout = (const float*)d_in[12];
  float* out = (float*)d_out;

  u32* h0m = (u32*)d_ws;                 // 2 parities x 512x256 tagged u32 (1 MB)
  u32* h1m = h0m + 2 * (size_t)MBOX_PAR; // 2 parities x 512x256 tagged u32 (1 MB)

  // Clear tags so a prior launch's tags can't alias this run's expected tags.
  hipMemsetAsync(h0m, 0, 4 * (size_t)MBOX_PAR * sizeof(u32), stream);
  arrnn_persistent<<<dim3(NGRP * GSZ), dim3(NTH), 0, stream>>>(
      X, ENC, MASK, wih0, whh0, bih0, bhh0, wih1, whh1, bih1, bhh1,
      wout, bout, out, h0m, h1m);
}

// Round 11
// 8478.805 us; speedup vs baseline: 1.7234x; 1.7234x over previous
//
#include <hip/hip_runtime.h>
#include <stdint.h>
#include <stddef.h>

typedef unsigned short u16;
typedef unsigned int u32;
typedef unsigned long long u64;
typedef __attribute__((ext_vector_type(8))) short short8;
typedef __attribute__((ext_vector_type(4))) float f32x4;
typedef __attribute__((ext_vector_type(2))) float f32x2;

#define B_    512
#define T_    1024
#define TM1_  1023
#define I_    32
#define E_    32
#define H_    256
#define GSZ   4           // blocks per group (dim slices)
#define NGRP  32          // number of groups
#define NTH   512         // threads per block (8 waves)
#define MBOX_PAR (B_ * H_)                 // u32 words per mailbox parity (131072)
#define OUTY_STRIDE (TM1_ * I_)            // 32736
#define OUTH_BASE ((size_t)B_ * TM1_ * I_) // 16760832

__device__ __forceinline__ u16 f2bf(float f) {
  union { float f; unsigned int i; } c;
  c.f = f;
  unsigned int x = c.i;
  x += 0x7FFFu + ((x >> 16) & 1u);   // round-to-nearest-even
  return (u16)(x >> 16);
}
__device__ __forceinline__ short8 ld8bf(const float* p) {
  short8 rv;
#pragma unroll
  for (int j = 0; j < 8; ++j) rv[j] = (short)f2bf(p[j]);
  return rv;
}
__device__ __forceinline__ float sigm(float x) { return 1.f / (1.f + __expf(-x)); }
__device__ __forceinline__ float tanh_fast(float x) {
  x = fminf(15.f, fmaxf(-15.f, x));
  float e = __expf(2.f * x);
  return (e - 1.f) / (e + 1.f);
}
// volatile => sc0 sc1 on gfx950: device/system scope, compiler no-reorder.
// PROVEN cross-XCD-correct (r0/r2/r4/r7/r10). sc0-only is CU scope (r5).
// u32 stores ONLY: the two kernels using volatile u64 stores (r8/r9) are the
// only two that ever container-killed; all six u32-store kernels ran.
__device__ __forceinline__ u64 ldq_cp(const u64* p) { return *(volatile const u64*)p; }
__device__ __forceinline__ void stw_cp(u32* p, u32 v) { *(volatile u32*)p = v; }

// XOR-swizzled byte offset into sW (whh1 r/z weight cache in LDS).
// Layout: [gi (0=r,1=z)][n 0..63 (block dim)][k16 0..31 (16B slot of K=256)].
// Swizzle ((n&7)<<4) spreads the 16-lane B-frag read (stride 512 B) across 8
// distinct 16B slots -> 2-way bank aliasing only (free, m136).
__device__ __forceinline__ int sw_off(int gi, int n, int k16) {
  int byte = ((gi << 6) + n) * 512 + (k16 << 4);
  return byte ^ ((n & 7) << 4);
}

// Persistent 2-layer GRU. Grid = 128 blocks, 512 thr (8 waves).
// 32 groups x 4 blocks. Group g owns batch rows [g*16,g*16+16); block r owns
// h-dims [r*64,r*64+64) of both layers.
//
// r11 = r10's passing structure with the weight-streaming bug fixed:
// r10 proved GSZ=4 halves coherent FETCH (4.59->2.31e6 KB) but its per-use
// streamed L1-r/z weights serialized ~8us/step of L2 latency (hbm_gbps 314,
// latency-bound). Here NO per-step global weight traffic:
//   gt0/gt1 (r/z): A: wfA[20] resident; B phase 7 (whh1 half): LDS sW (64KB,
//                  loaded once, swizzled); B phase 9 (wih1 half): wfB[16]
//                  resident (36 frags total; r10 allocated 44 fine).
//   gt2 (i_n): wfA[4] + wfB[16] (wih1) + wfY[8] resident.
//   gt3 (h_n): wfA[16] (whh0) + wfB[16] (whh1) resident.
//
// Sync: TAGGED MAILBOXES (r4, proven): word = bf16(h)<<16 | (step+1).
// Consumer polls its own 8 words (4 u64 loads) — the detecting load IS the
// data (1 RT/hop). Parity double-buffer bounds producer lead. Hang-proof
// bounded spins; s_sleep(4) re-poll backoff; publishes are two stw_cp u32.
__global__ __launch_bounds__(NTH, 1)
void arrnn_persistent(
    const float* __restrict__ X, const float* __restrict__ ENC, const int* __restrict__ MASK,
    const float* __restrict__ wih0, const float* __restrict__ whh0,
    const float* __restrict__ bih0, const float* __restrict__ bhh0,
    const float* __restrict__ wih1, const float* __restrict__ whh1,
    const float* __restrict__ bih1, const float* __restrict__ bhh1,
    const float* __restrict__ wout, const float* __restrict__ bout,
    float* __restrict__ out, u32* __restrict__ h0m, u32* __restrict__ h1m)
{
  __shared__ __align__(16) u16 sW[2 * 64 * 256];   // 65536 B whh1 r/z cache
  __shared__ __align__(16) u16 sH0buf[16 * 264];   // 8448 B  h0 staged
  __shared__ __align__(16) u16 sH1buf[16 * 264];   // 8448 B  h1 staged
  __shared__ __align__(16) u16 sXE[16 * 72];       // 2304 B  [x|e]
  __shared__ float sG[4 * 16 * 68];                // 17408 B gates
  __shared__ float sH0loc[1024];                   // 4096 B  fp32 carry (16x64)
  __shared__ float sH1loc[1024];
  __shared__ float sY[16 * 36];                    // 2304 B
  __shared__ int   sMk[16];

  const int tid  = threadIdx.x;
  const int w    = tid >> 6;          // wave 0..7
  const int lane = tid & 63;
  const int quad = lane >> 4;         // 0..3
  const int l15  = lane & 15;
  const int g    = blockIdx.x >> 2;   // group 0..31
  const int r    = blockIdx.x & 3;    // slice 0..3
  const int hs   = r << 6;            // h-dim base of this block's 64-dim slice
  const int row0 = g << 4;            // batch row base of group (16 rows)
  const int gt   = w >> 1;            // 0=r, 1=z, 2=i_n, 3=h_n
  const int P    = w & 1;             // N32-half: dims [P*32, P*32+32)
  const int toff = P << 5;
  const int crow = tid >> 5;          // staging/combine: row 0..15
  const int p32  = tid & 31;          // staging: u64-quad idx / combine: dim-pair

  short8 zero8 = {0, 0, 0, 0, 0, 0, 0, 0};

  // ---- preload resident weight B-fragments (fp32 -> bf16, once) ----
  const int n0 = hs + toff + l15;     // tile j=0 gate-dim (within 256)
  const int n1 = n0 + 16;             // tile j=1 gate-dim

  short8 wfA[20];
#pragma unroll
  for (int i = 0; i < 20; ++i) wfA[i] = zero8;
  short8 wfB[16];
#pragma unroll
  for (int i = 0; i < 16; ++i) wfB[i] = zero8;
  short8 wfY[8];
#pragma unroll
  for (int i = 0; i < 8; ++i) wfY[i] = zero8;

  float boutv = 0.f;
  if (gt <= 1) {
    const int gb = (gt == 1) ? 256 : 0;
#pragma unroll
    for (int j = 0; j < 2; ++j) {
      const int n = j ? n1 : n0;
#pragma unroll
      for (int kk = 0; kk < 10; ++kk) {          // A: L0 r/z, K=320
        const int k = kk * 32 + quad * 8;
        const float* p = (kk < 2) ? (wih0 + (gb + n) * 64 + k)
                                  : (whh0 + (gb + n) * 256 + (k - 64));
        wfA[j * 10 + kk] = ld8bf(p);
      }
#pragma unroll
      for (int kk = 0; kk < 8; ++kk)             // B ph9: L1 r/z over h0 (wih1)
        wfB[j * 8 + kk] = ld8bf(wih1 + (gb + n) * 256 + kk * 32 + quad * 8);
    }
  } else if (gt == 2) {
#pragma unroll
    for (int j = 0; j < 2; ++j) {
      const int n = j ? n1 : n0;
#pragma unroll
      for (int kk = 0; kk < 2; ++kk)             // A: L0 i_n (xe only)
        wfA[j * 2 + kk] = ld8bf(wih0 + (512 + n) * 64 + kk * 32 + quad * 8);
#pragma unroll
      for (int kk = 0; kk < 8; ++kk)             // B ph9: L1 i_n over h0
        wfB[j * 8 + kk] = ld8bf(wih1 + (512 + n) * 256 + kk * 32 + quad * 8);
    }
    const int ycol = (P << 4) + l15;             // readout cols
#pragma unroll
    for (int kk = 0; kk < 8; ++kk)
      wfY[kk] = ld8bf(wout + ycol * 256 + kk * 32 + quad * 8);
    boutv = bout[ycol];
  } else {                                        // gt == 3
#pragma unroll
    for (int j = 0; j < 2; ++j) {
      const int n = j ? n1 : n0;
#pragma unroll
      for (int kk = 0; kk < 8; ++kk)             // A: L0 h_n over h0
        wfA[j * 8 + kk] = ld8bf(whh0 + (512 + n) * 64 * 4 + kk * 32 + quad * 8);
#pragma unroll
      for (int kk = 0; kk < 8; ++kk)             // B ph7: L1 h_n over h1
        wfB[j * 8 + kk] = ld8bf(whh1 + (512 + n) * 256 + kk * 32 + quad * 8);
    }
  }

  // biases: combine thread handles dims bd0 = hs+2*p32, bd1 = bd0+1
  const int bd0 = hs + 2 * p32, bd1 = bd0 + 1;
  const float b0r0 = bih0[bd0] + bhh0[bd0],             b0r1 = bih0[bd1] + bhh0[bd1];
  const float b0z0 = bih0[256 + bd0] + bhh0[256 + bd0], b0z1 = bih0[256 + bd1] + bhh0[256 + bd1];
  const float b0i0 = bih0[512 + bd0],                   b0i1 = bih0[512 + bd1];
  const float b0h0 = bhh0[512 + bd0],                   b0h1 = bhh0[512 + bd1];
  const float b1r0 = bih1[bd0] + bhh1[bd0],             b1r1 = bih1[bd1] + bhh1[bd1];
  const float b1z0 = bih1[256 + bd0] + bhh1[256 + bd0], b1z1 = bih1[256 + bd1] + bhh1[256 + bd1];
  const float b1i0 = bih1[512 + bd0],                   b1i1 = bih1[512 + bd1];
  const float b1h0 = bhh1[512 + bd0],                   b1h1 = bhh1[512 + bd1];

  // ---- fill sW (whh1 r/z slice, swizzled) + zero LDS h bufs + carries ----
  for (int s = tid; s < 4096; s += NTH) {         // 4096 16B-slots
    const int gi = s >> 11, n = (s >> 5) & 63, k16 = s & 31;
    short8 v = ld8bf(whh1 + ((gi << 8) + hs + n) * 256 + (k16 << 3));
    *(short8*)((char*)sW + sw_off(gi, n, k16)) = v;
  }
  for (int i = tid; i < 2112; i += NTH) {
    ((u32*)sH0buf)[i] = 0u;
    ((u32*)sH1buf)[i] = 0u;
  }
  for (int i = tid; i < 1024; i += NTH) { sH0loc[i] = 0.f; sH1loc[i] = 0.f; }
  __syncthreads();

  int alive = 1;
  const int b = row0 + crow;          // this thread's staging/combine batch row

  // Poll own 8 words (tag == exp in every word), then unpack bf16 payload.
#define SPIN_STAGE(mboxu32, expTag, dstbuf)                                      \
  do {                                                                           \
    const u64* qp = (const u64*)(mboxu32) + (size_t)b * 128 + p32 * 4;           \
    const u64 tagp = (u64)(u32)(expTag) | ((u64)(u32)(expTag) << 32);            \
    u64 q0, q1, q2, q3;                                                          \
    int it = 0;                                                                  \
    for (;;) {                                                                   \
      q0 = ldq_cp(qp); q1 = ldq_cp(qp + 1); q2 = ldq_cp(qp + 2); q3 = ldq_cp(qp + 3); \
      u64 dd = ((q0 ^ tagp) | (q1 ^ tagp) | (q2 ^ tagp) | (q3 ^ tagp))           \
               & 0x0000FFFF0000FFFFull;                                          \
      if (dd == 0 || !alive) break;                                              \
      __builtin_amdgcn_s_sleep(4);                                               \
      if (++it > (1 << 15)) { alive = 0; break; }                                \
    }                                                                            \
    short8 sv;                                                                   \
    sv[0] = (short)(u16)(q0 >> 16); sv[1] = (short)(u16)(q0 >> 48);              \
    sv[2] = (short)(u16)(q1 >> 16); sv[3] = (short)(u16)(q1 >> 48);              \
    sv[4] = (short)(u16)(q2 >> 16); sv[5] = (short)(u16)(q2 >> 48);              \
    sv[6] = (short)(u16)(q3 >> 16); sv[7] = (short)(u16)(q3 >> 48);              \
    *(short8*)((dstbuf) + crow * 264 + p32 * 8) = sv;                            \
  } while (0)

  for (int t = 0; t < 1024; ++t) {
    const int par = t & 1;

    // ---- (a) stage x/e/mask into sXE (masked-x cols filled later from y) ----
    if (t < 1023) {
      if (p32 < 16) {
        int mk = 1;
        if (t > 0) mk = (MASK[b * T_ + t] != 0);
        f32x2 xld = *(const f32x2*)(X + ((size_t)b * T_ + t) * I_ + 2 * p32);
        if (mk) { sXE[crow * 72 + 2 * p32] = f2bf(xld.x);
                  sXE[crow * 72 + 2 * p32 + 1] = f2bf(xld.y); }
        if (p32 == 0) sMk[crow] = mk;
      } else {
        const int c2 = p32 - 16;
        f32x2 eld = *(const f32x2*)(ENC + ((size_t)b * T_ + t + 1) * E_ + 2 * c2);
        sXE[crow * 72 + 32 + 2 * c2] = f2bf(eld.x);
        sXE[crow * 72 + 32 + 2 * c2 + 1] = f2bf(eld.y);
      }
    }

    // ---- (1) phase A, h0(t-1)-part GEMM (sH0buf stable since prev step) ----
    f32x4 a0 = {0.f, 0.f, 0.f, 0.f}, a1 = {0.f, 0.f, 0.f, 0.f};
    if (t < 1023) {
      const u16* ah = sH0buf + l15 * 264 + quad * 8;
      if (gt <= 1) {
#pragma unroll
        for (int kk = 2; kk < 10; ++kk) {
          short8 af = *(const short8*)(ah + (kk - 2) * 32);
          a0 = __builtin_amdgcn_mfma_f32_16x16x32_bf16(af, wfA[kk], a0, 0, 0, 0);
          a1 = __builtin_amdgcn_mfma_f32_16x16x32_bf16(af, wfA[10 + kk], a1, 0, 0, 0);
        }
      } else if (gt == 3) {
#pragma unroll
        for (int kk = 0; kk < 8; ++kk) {
          short8 af = *(const short8*)(ah + kk * 32);
          a0 = __builtin_amdgcn_mfma_f32_16x16x32_bf16(af, wfA[kk], a0, 0, 0, 0);
          a1 = __builtin_amdgcn_mfma_f32_16x16x32_bf16(af, wfA[8 + kk], a1, 0, 0, 0);
        }
      }
    }

    // ---- (2) poll h1(t-1) mailbox (tag t), stage sH1buf ----
    if (t > 0) SPIN_STAGE(h1m + (size_t)par * MBOX_PAR, t, sH1buf);
    __syncthreads();   // B1

    // ---- (3) readout y(t-1): gt==2 waves ----
    if (t > 0 && gt == 2) {
      const u16* ap = sH1buf + l15 * 264 + quad * 8;
      f32x4 ay = {0.f, 0.f, 0.f, 0.f};
#pragma unroll
      for (int kk = 0; kk < 8; ++kk)
        ay = __builtin_amdgcn_mfma_f32_16x16x32_bf16(
            *(const short8*)(ap + kk * 32), wfY[kk], ay, 0, 0, 0);
#pragma unroll
      for (int rg = 0; rg < 4; ++rg)
        sY[(quad * 4 + rg) * 36 + (P << 4) + l15] = ay[rg] + boutv;
    }
    __syncthreads();   // B2

    // ---- (4) write out y(t-1); feed masked-x columns of sXE from y ----
    if (t > 0) {
      if (tid < 128) {
        const int lr = (r << 2) + (tid >> 5);   // this block's 4 rows
        const int lc = tid & 31;
        out[(size_t)(row0 + lr) * OUTY_STRIDE + (size_t)(t - 1) * I_ + lc] =
            sY[lr * 36 + lc];
      }
      if (t < 1023 && p32 < 16 && !sMk[crow]) {
        sXE[crow * 72 + 2 * p32]     = f2bf(sY[crow * 36 + 2 * p32]);
        sXE[crow * 72 + 2 * p32 + 1] = f2bf(sY[crow * 36 + 2 * p32 + 1]);
      }
    }
    if (t == 1023) break;
    __syncthreads();   // B3

    // ---- (5) phase A, xe-part GEMM + publish gates (gate idx = gt) ----
    {
      const u16* ax = sXE + l15 * 72 + quad * 8;
      if (gt <= 1) {
#pragma unroll
        for (int kk = 0; kk < 2; ++kk) {
          short8 af = *(const short8*)(ax + kk * 32);
          a0 = __builtin_amdgcn_mfma_f32_16x16x32_bf16(af, wfA[kk], a0, 0, 0, 0);
          a1 = __builtin_amdgcn_mfma_f32_16x16x32_bf16(af, wfA[10 + kk], a1, 0, 0, 0);
        }
      } else if (gt == 2) {
#pragma unroll
        for (int kk = 0; kk < 2; ++kk) {
          short8 af = *(const short8*)(ax + kk * 32);
          a0 = __builtin_amdgcn_mfma_f32_16x16x32_bf16(af, wfA[kk], a0, 0, 0, 0);
          a1 = __builtin_amdgcn_mfma_f32_16x16x32_bf16(af, wfA[2 + kk], a1, 0, 0, 0);
        }
      }
#pragma unroll
      for (int rg = 0; rg < 4; ++rg) {
        const int row = quad * 4 + rg;
        sG[(gt * 16 + row) * 68 + toff + l15]      = a0[rg];
        sG[(gt * 16 + row) * 68 + toff + 16 + l15] = a1[rg];
      }
    }
    __syncthreads();   // B4

    // ---- (6) combine -> h0(t); two tagged stw_cp per thread ----
    {
      const int d0 = 2 * p32, d1 = d0 + 1;
      const float gr0 = sG[(0 * 16 + crow) * 68 + d0] + b0r0;
      const float gz0 = sG[(1 * 16 + crow) * 68 + d0] + b0z0;
      const float gi0 = sG[(2 * 16 + crow) * 68 + d0] + b0i0;
      const float gh0 = sG[(3 * 16 + crow) * 68 + d0] + b0h0;
      const float gr1 = sG[(0 * 16 + crow) * 68 + d1] + b0r1;
      const float gz1 = sG[(1 * 16 + crow) * 68 + d1] + b0z1;
      const float gi1 = sG[(2 * 16 + crow) * 68 + d1] + b0i1;
      const float gh1 = sG[(3 * 16 + crow) * 68 + d1] + b0h1;
      const float rr0 = sigm(gr0), rr1 = sigm(gr1);
      const float zz0 = sigm(gz0), zz1 = sigm(gz1);
      const float nn0 = tanh_fast(gi0 + rr0 * gh0);
      const float nn1 = tanh_fast(gi1 + rr1 * gh1);
      const float hv0 = (1.f - zz0) * nn0 + zz0 * sH0loc[crow * 64 + d0];
      const float hv1 = (1.f - zz1) * nn1 + zz1 * sH0loc[crow * 64 + d1];
      sH0loc[crow * 64 + d0] = hv0;
      sH0loc[crow * 64 + d1] = hv1;
      u32* dst = h0m + (size_t)(par ^ 1) * MBOX_PAR + (size_t)b * H_ + hs + d0;
      stw_cp(dst,     ((u32)f2bf(hv0) << 16) | (u32)(t + 1));
      stw_cp(dst + 1, ((u32)f2bf(hv1) << 16) | (u32)(t + 1));
    }

    // ---- (7) phase B, h1(t-1)-part GEMM (overlaps the h0 hop) ----
    f32x4 c0 = {0.f, 0.f, 0.f, 0.f}, c1 = {0.f, 0.f, 0.f, 0.f};
    {
      const u16* a1p = sH1buf + l15 * 264 + quad * 8;
      if (gt <= 1) {           // L1 r/z, whh1 half: LDS sW (swizzled)
#pragma unroll
        for (int kk = 0; kk < 8; ++kk) {
          short8 af  = *(const short8*)(a1p + kk * 32);
          short8 bf0 = *(const short8*)((const char*)sW + sw_off(gt, toff + l15,      kk * 4 + quad));
          short8 bf1 = *(const short8*)((const char*)sW + sw_off(gt, toff + 16 + l15, kk * 4 + quad));
          c0 = __builtin_amdgcn_mfma_f32_16x16x32_bf16(af, bf0, c0, 0, 0, 0);
          c1 = __builtin_amdgcn_mfma_f32_16x16x32_bf16(af, bf1, c1, 0, 0, 0);
        }
      } else if (gt == 3) {    // L1 h_n over h1: resident
#pragma unroll
        for (int kk = 0; kk < 8; ++kk) {
          short8 af = *(const short8*)(a1p + kk * 32);
          c0 = __builtin_amdgcn_mfma_f32_16x16x32_bf16(af, wfB[kk], c0, 0, 0, 0);
          c1 = __builtin_amdgcn_mfma_f32_16x16x32_bf16(af, wfB[8 + kk], c1, 0, 0, 0);
        }
      }
    }

    // ---- (8) poll h0(t) mailbox (tag t+1), stage sH0buf ----
    SPIN_STAGE(h0m + (size_t)(par ^ 1) * MBOX_PAR, t + 1, sH0buf);
    __syncthreads();   // B5 (also separates (6) sG reads from (9) writes)

    // ---- (9) phase B, h0(t)-part GEMM + publish gates (gate idx = gt) ----
    {
      const u16* a0p = sH0buf + l15 * 264 + quad * 8;
      if (gt <= 2) {           // L1 r/z/i_n over h0: resident wfB
#pragma unroll
        for (int kk = 0; kk < 8; ++kk) {
          short8 af = *(const short8*)(a0p + kk * 32);
          c0 = __builtin_amdgcn_mfma_f32_16x16x32_bf16(af, wfB[kk], c0, 0, 0, 0);
          c1 = __builtin_amdgcn_mfma_f32_16x16x32_bf16(af, wfB[8 + kk], c1, 0, 0, 0);
        }
      }
#pragma unroll
      for (int rg = 0; rg < 4; ++rg) {
        const int row = quad * 4 + rg;
        sG[(gt * 16 + row) * 68 + toff + l15]      = c0[rg];
        sG[(gt * 16 + row) * 68 + toff + 16 + l15] = c1[rg];
      }
    }
    __syncthreads();   // B6

    // ---- (10) combine -> h1(t); two tagged stw_cp per thread ----
    {
      const int d0 = 2 * p32, d1 = d0 + 1;
      const float gr0 = sG[(0 * 16 + crow) * 68 + d0] + b1r0;
      const float gz0 = sG[(1 * 16 + crow) * 68 + d0] + b1z0;
      const float gi0 = sG[(2 * 16 + crow) * 68 + d0] + b1i0;
      const float gh0 = sG[(3 * 16 + crow) * 68 + d0] + b1h0;
      const float gr1 = sG[(0 * 16 + crow) * 68 + d1] + b1r1;
      const float gz1 = sG[(1 * 16 + crow) * 68 + d1] + b1z1;
      const float gi1 = sG[(2 * 16 + crow) * 68 + d1] + b1i1;
      const float gh1 = sG[(3 * 16 + crow) * 68 + d1] + b1h1;
      const float rr0 = sigm(gr0), rr1 = sigm(gr1);
      const float zz0 = sigm(gz0), zz1 = sigm(gz1);
      const float nn0 = tanh_fast(gi0 + rr0 * gh0);
      const float nn1 = tanh_fast(gi1 + rr1 * gh1);
      const float hv0 = (1.f - zz0) * nn0 + zz0 * sH1loc[crow * 64 + d0];
      const float hv1 = (1.f - zz1) * nn1 + zz1 * sH1loc[crow * 64 + d1];
      sH1loc[crow * 64 + d0] = hv0;
      sH1loc[crow * 64 + d1] = hv1;
      u32* dst = h1m + (size_t)(par ^ 1) * MBOX_PAR + (size_t)b * H_ + hs + d0;
      stw_cp(dst,     ((u32)f2bf(hv0) << 16) | (u32)(t + 1));
      stw_cp(dst + 1, ((u32)f2bf(hv1) << 16) | (u32)(t + 1));
    }
  }

  // final hidden state h1(T-2): own fp32 slice (2 dims/thread)
  out[OUTH_BASE + (size_t)b * H_ + hs + 2 * p32]     = sH1loc[crow * 64 + 2 * p32];
  out[OUTH_BASE + (size_t)b * H_ + hs + 2 * p32 + 1] = sH1loc[crow * 64 + 2 * p32 + 1];
#undef SPIN_STAGE
}

extern "C" void kernel_launch(void* const* d_in, const int* in_sizes, int n_in,
                              void* d_out, int out_size, void* d_ws, size_t ws_size,
                              hipStream_t stream) {
  (void)in_sizes; (void)n_in; (void)out_size; (void)ws_size;
  const float* X    = (const float*)d_in[0];
  const float* ENC  = (const float*)d_in[1];
  const int*   MASK = (const int*)d_in[2];
  const float* wih0 = (const float*)d_in[3];
  const float* whh0 = (const float*)d_in[4];
  const float* bih0 = (const float*)d_in[5];
  const float* bhh0 = (const float*)d_in[6];
  const float* wih1 = (const float*)d_in[7];
  const float* whh1 = (const float*)d_in[8];
  const float* bih1 = (const float*)d_in[9];
  const float* bhh1 = (const float*)d_in[10];
  const float* wout = (const float*)d_in[11];
  const float* bout = (const float*)d_in[12];
  float* out = (float*)d_out;

  u32* h0m = (u32*)d_ws;                 // 2 parities x 512x256 tagged u32 (1 MB)
  u32* h1m = h0m + 2 * (size_t)MBOX_PAR; // 2 parities x 512x256 tagged u32 (1 MB)

  // Clear tags so a prior launch's tags can't alias this run's expected tags.
  hipMemsetAsync(h0m, 0, 4 * (size_t)MBOX_PAR * sizeof(u32), stream);
  arrnn_persistent<<<dim3(NGRP * GSZ), dim3(NTH), 0, stream>>>(
      X, ENC, MASK, wih0, whh0, bih0, bhh0, wih1, whh1, bih1, bhh1,
      wout, bout, out, h0m, h1m);
}